// Round 3
// baseline (625.367 us; speedup 1.0000x reference)
//
#include <hip/hip_runtime.h>

// LSTM B=2048, T=1024, H=50. Round 16: single-wave recurrence, ZERO barriers.
//  - 1 wave/block, BW=2 batches, grid=1024 -> 4 independent waves/CU (1/SIMD).
//  - h redistribution via 8x ds_bpermute (in-wave gather), replacing
//    cvt->ds_write->drain->s_barrier->ds_read. No __syncthreads in the loop.
//  - B cols = 2 batches x 8 replica groups (ts). Lane (kq, ts, bl) owns units
//    j0=4ts+kq (tile ts) and j1=32+4ts+kq (tile ts+8). Packed h {f16 j0, f16 j1}
//    means gather e from lane {kq_s=e&3, ts_s=2kq+(e>>2), bl} yields
//    {h[8kq+e], h[8kq+e+32]} -> feeds BOTH split-K halves with no unpack:
//    A k-slots use the interleaved map kappa = 8kq + 4kf + (p>>1) + 32*(p&1)
//    (A and B agree on any slot<->unit bijection, so this is free).
//  - 13 tiles x split-K-2 = 26 MFMAs/wave/step; 44-cndmask tree selects the
//    lane's 2 accumulators; gx (exact f32, from prefetched x) added post-select.
//  - Pad units (j>=50): A rows zero + zc zero -> gates 0 -> h stays 0; invalid
//    s1 lanes additionally force hh1=0 at pack.
//  - Epilogue unchanged (exp2-only, scaled c2 = 2*log2e*c).

#define H     50
#define TT    1024
#define BATCH 2048
#define BW    2
#define NT    13      // gate-row tiles of 16

typedef float        f32x4 __attribute__((ext_vector_type(4)));
typedef _Float16     f16x8 __attribute__((ext_vector_type(8)));
typedef unsigned int u32x4 __attribute__((ext_vector_type(4)));

__global__ __launch_bounds__(64, 1) void lstm_kernel(
    const float* __restrict__ x,      // [B, T]
    const float* __restrict__ W_ih,   // [200]
    const float* __restrict__ W_hh,   // [200, 50]
    const float* __restrict__ b_ih,   // [200]
    const float* __restrict__ b_hh,   // [200]
    const float* __restrict__ W_lin,  // [50]
    const float* __restrict__ b_lin,  // [1]
    float* __restrict__ out)          // [B]
{
    __shared__ float XT[TT + 1][BW];  // x per (t, b), +1 pad row for prefetch

    const int lane = threadIdx.x & 63;
    const int kq   = lane >> 4;
    const int L15  = lane & 15;
    const int ts   = L15 >> 1;        // replica group 0..7
    const int bl   = L15 & 1;         // batch 0..1
    const int b0   = blockIdx.x * BW;

    const float LOG2E  = 1.4426950408889634f;
    const float LOG2E2 = 2.8853900817779268f;

    // ---- A fragments: 13 tiles x 2 halves, interleaved k-slot map ----
    // half kf, f16 slot p: kappa = 8*kq + 4*kf + (p>>1) + 32*(p&1)
    f16x8 A[NT][2];
    #pragma unroll
    for (int tt = 0; tt < NT; ++tt) {
        const int m  = tt * 16 + L15;         // permuted gate-row n' = 4j+g
        const int jm = m >> 2, gm = m & 3;
        const bool v = (jm < H);
        const float s = (gm == 2) ? LOG2E2 : -LOG2E;
        #pragma unroll
        for (int kf = 0; kf < 2; ++kf) {
            f16x8 vv;
            #pragma unroll
            for (int p = 0; p < 8; ++p) {
                const int kap = 8 * kq + 4 * kf + (p >> 1) + 32 * (p & 1);
                _Float16 val = (_Float16)0.f;
                if (v && kap < H) val = (_Float16)(s * W_hh[(gm * H + jm) * H + kap]);
                vv[p] = val;
            }
            A[tt][kf] = vv;
        }
    }

    // ---- owned units + exact f32 x-path coefficients ----
    const int  j0  = 4 * ts + kq;             // 0..31, always < 50
    const int  j1  = 32 + 4 * ts + kq;        // 32..63
    const bool jv1 = (j1 < H);
    float zw0[4], zb0[4], zw1[4], zb1[4];
    #pragma unroll
    for (int r = 0; r < 4; ++r) {
        const float s = (r == 2) ? LOG2E2 : -LOG2E;
        zw0[r] = s * W_ih[r * H + j0];
        zb0[r] = s * (b_ih[r * H + j0] + b_hh[r * H + j0]);
        zw1[r] = jv1 ? s * W_ih[r * H + j1] : 0.f;
        zb1[r] = jv1 ? s * (b_ih[r * H + j1] + b_hh[r * H + j1]) : 0.f;
    }
    const float wl0 = W_lin[j0];
    const float wl1 = jv1 ? W_lin[j1] : 0.f;

    // ---- bpermute byte-addresses: gather e pulls from lane
    //      16*(e&3) + 2*(2*kq + (e>>2)) + bl ----
    int gaddr[8];
    #pragma unroll
    for (int e = 0; e < 8; ++e) {
        const int src = 16 * (e & 3) + 2 * (2 * kq + (e >> 2)) + bl;
        gaddr[e] = src << 2;
    }

    // ---- XT init (single wave: no barrier needed, DS is in-order) ----
    for (int i = lane; i < TT * BW; i += 64) {
        const int bb = i >> 10, t = i & (TT - 1);
        XT[t][bb] = x[(size_t)(b0 + bb) * TT + t];
    }
    if (lane < BW) XT[TT][lane] = 0.f;
    __syncthreads();   // one-time, trivial for a single wave

    float c2a = 0.f, c2b = 0.f;        // scaled cell states (2*log2e*c)
    float h0f = 0.f, h1f = 0.f;
    int   P0  = 0;                     // packed {f16 h[j0], f16 h[j1]}
    float xt_cur = XT[0][bl];

    const bool tb0 = (ts & 1) != 0;
    const bool tb1 = (ts & 2) != 0;
    const bool tb2 = (ts & 4) != 0;

    #pragma unroll 1
    for (int t = 0; t < TT; ++t) {
        // ---- in-wave gather of h into B-fragment layout ----
        int g[8];
        #pragma unroll
        for (int e = 0; e < 8; ++e)
            g[e] = __builtin_amdgcn_ds_bpermute(gaddr[e], P0);
        const float xt_nxt = XT[t + 1][bl];   // prefetch (off-chain)

        // gx for this lane's 2 units (off critical path)
        float gz0[4], gz1[4];
        #pragma unroll
        for (int r = 0; r < 4; ++r) {
            gz0[r] = __builtin_fmaf(zw0[r], xt_cur, zb0[r]);
            gz1[r] = __builtin_fmaf(zw1[r], xt_cur, zb1[r]);
        }

        u32x4 b0w, b1w;
        b0w[0] = g[0]; b0w[1] = g[1]; b0w[2] = g[2]; b0w[3] = g[3];
        b1w[0] = g[4]; b1w[1] = g[5]; b1w[2] = g[6]; b1w[3] = g[7];
        const f16x8 Bh0 = __builtin_bit_cast(f16x8, b0w);
        const f16x8 Bh1 = __builtin_bit_cast(f16x8, b1w);

        // ---- 26 MFMAs: 13 independent 2-deep split-K chains ----
        const f32x4 zz = {0.f, 0.f, 0.f, 0.f};
        f32x4 acc[NT];
        #pragma unroll
        for (int tt = 0; tt < NT; ++tt)
            acc[tt] = __builtin_amdgcn_mfma_f32_16x16x32_f16(A[tt][0], Bh0, zz, 0, 0, 0);
        #pragma unroll
        for (int tt = 0; tt < NT; ++tt)
            acc[tt] = __builtin_amdgcn_mfma_f32_16x16x32_f16(A[tt][1], Bh1, acc[tt], 0, 0, 0);

        // ---- select: s0 = acc[ts], s1 = acc[8 + min(ts,4)] ----
        float ga[4], gb[4];
        #pragma unroll
        for (int r = 0; r < 4; ++r) {
            const float m01 = tb0 ? acc[1][r]  : acc[0][r];
            const float m23 = tb0 ? acc[3][r]  : acc[2][r];
            const float m45 = tb0 ? acc[5][r]  : acc[4][r];
            const float m67 = tb0 ? acc[7][r]  : acc[6][r];
            const float m03 = tb1 ? m23 : m01;
            const float m47 = tb1 ? m67 : m45;
            ga[r] = (tb2 ? m47 : m03) + gz0[r];

            const float n89 = tb0 ? acc[9][r]  : acc[8][r];
            const float nAB = tb0 ? acc[11][r] : acc[10][r];
            const float n8B = tb1 ? nAB : n89;
            gb[r] = (tb2 ? acc[12][r] : n8B) + gz1[r];   // ts>=5: garbage, zeroed at pack
        }

        // ---- fused epilogue x2 (exp2-only, scaled-c2 form) ----
        {
            const float Ei = __builtin_amdgcn_exp2f(ga[0]);
            const float Ef = __builtin_amdgcn_exp2f(ga[1]);
            const float Eg = __builtin_amdgcn_exp2f(ga[2]);
            const float Eo = __builtin_amdgcn_exp2f(ga[3]);
            const float P  = (1.0f + Ei) * (1.0f + Eg);
            const float Q  = 1.0f + Ef;
            const float Q2 = __builtin_fmaf(LOG2E2, Ef, LOG2E2);
            const float num = __builtin_fmaf(c2a, P, (Eg - 1.0f) * Q2);
            c2a = num * __builtin_amdgcn_rcpf(P * Q);
            const float ca = fminf(c2a, 80.0f);
            const float Ec = __builtin_amdgcn_exp2f(ca);
            h0f = (Ec - 1.0f) * __builtin_amdgcn_rcpf((1.0f + Eo) * (1.0f + Ec));
        }
        {
            const float Ei = __builtin_amdgcn_exp2f(gb[0]);
            const float Ef = __builtin_amdgcn_exp2f(gb[1]);
            const float Eg = __builtin_amdgcn_exp2f(gb[2]);
            const float Eo = __builtin_amdgcn_exp2f(gb[3]);
            const float P  = (1.0f + Ei) * (1.0f + Eg);
            const float Q  = 1.0f + Ef;
            const float Q2 = __builtin_fmaf(LOG2E2, Ef, LOG2E2);
            const float num = __builtin_fmaf(c2b, P, (Eg - 1.0f) * Q2);
            c2b = num * __builtin_amdgcn_rcpf(P * Q);
            const float ca = fminf(c2b, 80.0f);
            const float Ec = __builtin_amdgcn_exp2f(ca);
            h1f = (Ec - 1.0f) * __builtin_amdgcn_rcpf((1.0f + Eo) * (1.0f + Ec));
        }

        // ---- pack new h (invalid s1 forced to 0) ----
        const _Float16 hh0 = (_Float16)h0f;
        const _Float16 hh1 = jv1 ? (_Float16)h1f : (_Float16)0.f;
        const unsigned int u0 = (unsigned int)__builtin_bit_cast(unsigned short, hh0);
        const unsigned int u1 = (unsigned int)__builtin_bit_cast(unsigned short, hh1);
        P0 = (int)(u0 | (u1 << 16));
        xt_cur = xt_nxt;
    }

    // ---- head: out[b] = b_lin + sum_j W_lin[j] * h[j][b] ----
    float p = __builtin_fmaf(wl0, h0f, wl1 * h1f);
    #pragma unroll
    for (int m = 2; m <= 32; m <<= 1) p += __shfl_xor(p, m, 64);
    if (lane < BW) out[b0 + lane] = p + b_lin[0];
}

extern "C" void kernel_launch(void* const* d_in, const int* in_sizes, int n_in,
                              void* d_out, int out_size, void* d_ws, size_t ws_size,
                              hipStream_t stream) {
    const float* x     = (const float*)d_in[0];
    const float* W_ih  = (const float*)d_in[1];
    const float* W_hh  = (const float*)d_in[2];
    const float* b_ih  = (const float*)d_in[3];
    const float* b_hh  = (const float*)d_in[4];
    const float* W_lin = (const float*)d_in[5];
    const float* b_lin = (const float*)d_in[6];
    float* out = (float*)d_out;

    dim3 grid(BATCH / BW);    // 1024 blocks, 4 per CU (1 wave per SIMD)
    dim3 block(64);           // 1 wave
    lstm_kernel<<<grid, block, 0, stream>>>(x, W_ih, W_hh, b_ih, b_hh,
                                            W_lin, b_lin, out);
}

// Round 4
// 427.968 us; speedup vs baseline: 1.4612x; 1.4612x over previous
//
#include <hip/hip_runtime.h>

// LSTM B=2048, T=1024, H=50. Round 17: minimize LDS-pipe pressure per step.
//  - 4 waves (256 thr), BW=8, 1 block/CU. Each wave owns 4 gate-row tiles
//    (NTILE=4); lane (kq, rp=L15>>3, bl=L15&7) consumes 2 units:
//    uA = 16w+4rp+kq (tile rp), uB = uA+8 (tile rp+2). 1-level select.
//  - Packed h-write: k-slot permutation kappa places a lane's 2 units in
//    adjacent slots -> ONE ds_write_b32 per lane. A-fragments follow kappa
//    (any slot<->unit bijection works as long as A and B agree).
//      slot s = 16w + 2*(2kq+rp) + d  <->  unit u = 16w + 4rp + kq + 8d
//  - x read from GLOBAL (L1-cached, prefetched 1 step ahead, off-chain):
//    XT LDS buffer and its per-step DS read deleted.
//  - DS ops/CU/step: 28 (R13) -> 12 (8x ds_read_b128 + 4x ds_write_b32).
//  - Keeps: 2-deep split-K MFMA chains, exact-f32 gx post-add, exp2-only
//    epilogue with pre-scaled cell state c2 = 2*log2e*c, f16 W_hh/h.

#define H     50
#define TT    1024
#define BATCH 2048
#define BW    8
#define NTHR  256     // 4 waves
#define NTILE 4
#define KP    80      // f16 per hb row (40-word stride, conflict-free pattern)

typedef float    f32x4 __attribute__((ext_vector_type(4)));
typedef _Float16 f16x8 __attribute__((ext_vector_type(8)));

__global__ __launch_bounds__(NTHR, 1) void lstm_kernel(
    const float* __restrict__ x,      // [B, T]
    const float* __restrict__ W_ih,   // [200]
    const float* __restrict__ W_hh,   // [200, 50]
    const float* __restrict__ b_ih,   // [200]
    const float* __restrict__ b_hh,   // [200]
    const float* __restrict__ W_lin,  // [50]
    const float* __restrict__ b_lin,  // [1]
    float* __restrict__ out)          // [B]
{
    __shared__ _Float16 hb[2][BW][KP];    // h (kappa-slot order), double-buffered
    __shared__ float    redW[4][BW];      // head reduction across waves

    const int tid  = threadIdx.x;
    const int wave = tid >> 6;
    const int lane = tid & 63;
    const int L15  = lane & 15;
    const int kq   = lane >> 4;
    const int rp   = L15 >> 3;            // replica/tile-select bit
    const int bl   = L15 & 7;             // batch
    const int b0   = blockIdx.x * BW;

    const float LOG2E  = 1.4426950408889634f;
    const float LOG2E2 = 2.8853900817779268f;

    // ---- A fragments: 4 tiles, rows n' = tg*16 + L15 (unit j = 4tg + L15>>2,
    //      gate g = L15&3), k-slots follow kappa ----
    f16x8 A[NTILE][2];
    #pragma unroll
    for (int tt = 0; tt < NTILE; ++tt) {
        const int tg = NTILE * wave + tt;
        const int jm = 4 * tg + (L15 >> 2);
        const int gm = L15 & 3;
        const bool v = (jm < H);
        const float s = (gm == 2) ? LOG2E2 : -LOG2E;
        #pragma unroll
        for (int kf = 0; kf < 2; ++kf) {
            f16x8 vv;
            #pragma unroll
            for (int e = 0; e < 8; ++e) {
                const int kap = kf * 32 + kq * 8 + e;
                // kappa: slot -> unit
                const int u = 16 * (kap >> 4) + 4 * ((kap >> 1) & 1)
                            + ((kap >> 2) & 3) + 8 * (kap & 1);
                _Float16 val = (_Float16)0.f;
                if (v && u < H) val = (_Float16)(s * W_hh[(gm * H + jm) * H + u]);
                vv[e] = val;
            }
            A[tt][kf] = vv;
        }
    }

    // ---- this lane's 2 units + exact f32 x-path coefficients ----
    const int  uA  = 16 * wave + 4 * rp + kq;    // from tile (local) rp
    const int  uB  = uA + 8;                     // from tile (local) rp+2
    const bool vA  = (uA < H);
    const bool vB  = (uB < H);
    float zwA[4], zbA[4], zwB[4], zbB[4];
    #pragma unroll
    for (int r = 0; r < 4; ++r) {
        const float s = (r == 2) ? LOG2E2 : -LOG2E;
        zwA[r] = vA ? s * W_ih[r * H + uA] : 0.f;
        zbA[r] = vA ? s * (b_ih[r * H + uA] + b_hh[r * H + uA]) : 0.f;
        zwB[r] = vB ? s * W_ih[r * H + uB] : 0.f;
        zbB[r] = vB ? s * (b_ih[r * H + uB] + b_hh[r * H + uB]) : 0.f;
    }
    const float wlA = vA ? W_lin[uA] : 0.f;
    const float wlB = vB ? W_lin[uB] : 0.f;

    // write slot (f16 index, even) for the packed {hA, hB} b32 store
    const int sw = 16 * wave + 2 * (2 * kq + rp);

    // per-lane global x pointer (batch bl of this block)
    const float* xg = x + (size_t)(b0 + bl) * TT;

    // ---- init: zero hb ----
    for (int i = tid; i < 2 * BW * KP; i += NTHR)
        ((_Float16*)hb)[i] = (_Float16)0.f;

    float c2A = 0.f, c2B = 0.f;        // scaled cell states (2*log2e*c)
    float hA = 0.f, hB = 0.f;
    float xcur = xg[0];
    __syncthreads();

    #pragma unroll 1
    for (int tbase = 0; tbase < TT; tbase += 2) {
        #pragma unroll
        for (int half = 0; half < 2; ++half) {
            const int t = tbase + half;
            const _Float16* hp = &hb[half][bl][0];        // cur buffer
            _Float16*       np = &hb[half ^ 1][bl][0];    // next buffer

            // ---- B fragments: 2x ds_read_b128 ----
            const f16x8 B0 = *(const f16x8*)(hp + kq * 8);
            const f16x8 B1 = *(const f16x8*)(hp + 32 + kq * 8);

            // ---- 8 MFMAs: 4 independent 2-deep split-K chains ----
            const f32x4 zz = {0.f, 0.f, 0.f, 0.f};
            f32x4 a0 = __builtin_amdgcn_mfma_f32_16x16x32_f16(A[0][0], B0, zz, 0, 0, 0);
            f32x4 a1 = __builtin_amdgcn_mfma_f32_16x16x32_f16(A[1][0], B0, zz, 0, 0, 0);
            f32x4 a2 = __builtin_amdgcn_mfma_f32_16x16x32_f16(A[2][0], B0, zz, 0, 0, 0);
            f32x4 a3 = __builtin_amdgcn_mfma_f32_16x16x32_f16(A[3][0], B0, zz, 0, 0, 0);
            a0 = __builtin_amdgcn_mfma_f32_16x16x32_f16(A[0][1], B1, a0, 0, 0, 0);
            a1 = __builtin_amdgcn_mfma_f32_16x16x32_f16(A[1][1], B1, a1, 0, 0, 0);
            a2 = __builtin_amdgcn_mfma_f32_16x16x32_f16(A[2][1], B1, a2, 0, 0, 0);
            a3 = __builtin_amdgcn_mfma_f32_16x16x32_f16(A[3][1], B1, a3, 0, 0, 0);

            // prefetch next x (global, L1-hit, off the critical chain)
            const float xnxt = xg[(t + 1) & (TT - 1)];

            // ---- 1-level select + exact f32 gx add ----
            const bool rb = (rp != 0);
            float ga[4], gb[4];
            #pragma unroll
            for (int r = 0; r < 4; ++r) {
                ga[r] = (rb ? a1[r] : a0[r]) + __builtin_fmaf(zwA[r], xcur, zbA[r]);
                gb[r] = (rb ? a3[r] : a2[r]) + __builtin_fmaf(zwB[r], xcur, zbB[r]);
            }

            // ---- fused epilogue x2 (exp2-only, scaled-c2 form) ----
            {
                const float Ei = __builtin_amdgcn_exp2f(ga[0]);
                const float Ef = __builtin_amdgcn_exp2f(ga[1]);
                const float Eg = __builtin_amdgcn_exp2f(ga[2]);
                const float Eo = __builtin_amdgcn_exp2f(ga[3]);
                const float P  = (1.0f + Ei) * (1.0f + Eg);
                const float Q  = 1.0f + Ef;
                const float Q2 = __builtin_fmaf(LOG2E2, Ef, LOG2E2);
                const float num = __builtin_fmaf(c2A, P, (Eg - 1.0f) * Q2);
                c2A = num * __builtin_amdgcn_rcpf(P * Q);
                const float ca = fminf(c2A, 80.0f);
                const float Ec = __builtin_amdgcn_exp2f(ca);
                hA = (Ec - 1.0f) * __builtin_amdgcn_rcpf((1.0f + Eo) * (1.0f + Ec));
            }
            {
                const float Ei = __builtin_amdgcn_exp2f(gb[0]);
                const float Ef = __builtin_amdgcn_exp2f(gb[1]);
                const float Eg = __builtin_amdgcn_exp2f(gb[2]);
                const float Eo = __builtin_amdgcn_exp2f(gb[3]);
                const float P  = (1.0f + Ei) * (1.0f + Eg);
                const float Q  = 1.0f + Ef;
                const float Q2 = __builtin_fmaf(LOG2E2, Ef, LOG2E2);
                const float num = __builtin_fmaf(c2B, P, (Eg - 1.0f) * Q2);
                c2B = num * __builtin_amdgcn_rcpf(P * Q);
                const float ca = fminf(c2B, 80.0f);
                const float Ec = __builtin_amdgcn_exp2f(ca);
                hB = (Ec - 1.0f) * __builtin_amdgcn_rcpf((1.0f + Eo) * (1.0f + Ec));
            }

            // ---- packed write: ONE ds_write_b32 {hA, hB} ----
            // pad units self-zero exactly (zero A rows + zero gz -> h == 0)
            const _Float16 fA = (_Float16)hA;
            const _Float16 fB = (_Float16)hB;
            const unsigned int pk =
                (unsigned int)__builtin_bit_cast(unsigned short, fA) |
                ((unsigned int)__builtin_bit_cast(unsigned short, fB) << 16);
            *(unsigned int*)(np + sw) = pk;
            __syncthreads();
            xcur = xnxt;
        }
    }

    // ---- head: out[b] = b_lin + sum_j W_lin[j] * h[j][b] ----
    float p = __builtin_fmaf(wlA, hA, wlB * hB);
    #pragma unroll
    for (int m = 8; m <= 32; m <<= 1) p += __shfl_xor(p, m, 64);
    if (lane < BW) redW[wave][lane] = p;     // lane == bl for lane<8
    __syncthreads();
    if (tid < BW) {
        out[b0 + tid] = b_lin[0] + redW[0][tid] + redW[1][tid]
                      + redW[2][tid] + redW[3][tid];
    }
}

extern "C" void kernel_launch(void* const* d_in, const int* in_sizes, int n_in,
                              void* d_out, int out_size, void* d_ws, size_t ws_size,
                              hipStream_t stream) {
    const float* x     = (const float*)d_in[0];
    const float* W_ih  = (const float*)d_in[1];
    const float* W_hh  = (const float*)d_in[2];
    const float* b_ih  = (const float*)d_in[3];
    const float* b_hh  = (const float*)d_in[4];
    const float* W_lin = (const float*)d_in[5];
    const float* b_lin = (const float*)d_in[6];
    float* out = (float*)d_out;

    dim3 grid(BATCH / BW);    // 256 blocks, 1 per CU
    dim3 block(NTHR);         // 4 waves
    lstm_kernel<<<grid, block, 0, stream>>>(x, W_ih, W_hh, b_ih, b_hh,
                                            W_lin, b_lin, out);
}

// Round 5
// 333.356 us; speedup vs baseline: 1.8760x; 1.2838x over previous
//
#include <hip/hip_runtime.h>

// LSTM B=2048, T=1024, H=50. Round 18: R13 skeleton (7 waves, BW=8, LDS XT,
// chained split-K, 1 block/CU) + zc C-operand trim.
//  - x/bias contribution folded into the MFMA C-operand init:
//    zc[r] = fma(zw[r], x_t, zb[r]) (exact f32, per-lane; each lane only
//    consumes its own unit's accumulator rows, so the "wrong" zc rows in the
//    discarded accumulator don't matter - verified in R14/R17).
//  - Deletes R13's k=56..60 B-slot machinery: no Bm cndmask merge between
//    ds_read and MFMA, no u32 XT pack/unpack, no hi/lo f16 compensation.
//    B1 is a plain ds_read_b128; XT stores plain f32, prefetched 1 step
//    ahead (zc inputs are old news -> off the critical chain).
//  - Keeps: chained split-K (R14 showed parallel+add is a net loss),
//    exp2-only epilogue with pre-scaled cell state c2 = 2*log2e*c,
//    KP=80 layout, one barrier per step, x2 unrolled halves.

#define H     50
#define TT    1024
#define BATCH 2048
#define BW    8
#define NTHR  448     // 7 waves
#define KP    80      // f16 per hb row (40-word stride, measured conflict-free)

typedef float    f32x4 __attribute__((ext_vector_type(4)));
typedef _Float16 f16x8 __attribute__((ext_vector_type(8)));

__global__ __launch_bounds__(NTHR, 1) void lstm_kernel(
    const float* __restrict__ x,      // [B, T]
    const float* __restrict__ W_ih,   // [200]
    const float* __restrict__ W_hh,   // [200, 50]
    const float* __restrict__ b_ih,   // [200]
    const float* __restrict__ b_hh,   // [200]
    const float* __restrict__ W_lin,  // [50]
    const float* __restrict__ b_lin,  // [1]
    float* __restrict__ out)          // [B]
{
    __shared__ _Float16 hb[2][BW][KP];    // h^T, double-buffered
    __shared__ float    XT[TT + 2][BW];   // x per (t, b), +2 pad rows
    __shared__ float    redH[H][BW];      // head reduction

    const int tid  = threadIdx.x;
    const int wave = tid >> 6;
    const int lane = tid & 63;
    const int L15  = lane & 15;
    const int kq   = lane >> 4;
    const int bl   = L15 & 7;
    const int b0   = blockIdx.x * BW;

    const int t0 = 2 * wave;              // tiles t0, t0+1 (wave 6: 12,13)

    const float LOG2E  = 1.4426950408889634f;
    const float LOG2E2 = 2.8853900817779268f;

    // ---- A fragments: scaled permuted W_hh rows (k 0..49 only), f16 ----
    f16x8 A[2][2];
    #pragma unroll
    for (int tt = 0; tt < 2; ++tt) {
        const int m  = (t0 + tt) * 16 + L15;  // permuted gate-row n' = 4j+g
        const int jm = m >> 2, gm = m & 3;
        const bool v = (jm < H);
        const float s = (gm == 2) ? LOG2E2 : -LOG2E;
        #pragma unroll
        for (int kf = 0; kf < 2; ++kf) {
            f16x8 vv;
            #pragma unroll
            for (int e = 0; e < 8; ++e) {
                const int k = kf * 32 + kq * 8 + e;
                _Float16 val = (_Float16)0.f;
                if (v && k < H) val = (_Float16)(s * W_hh[(gm * H + jm) * H + k]);
                vv[e] = val;
            }
            A[tt][kf] = vv;
        }
    }

    // ---- this lane's unit + exact f32 x-path coefficients (C-init) ----
    const int  j  = 8 * wave + ((L15 >> 3) << 2) + kq;   // 0..55 (50-55 pad)
    const bool jv = (j < H);
    const float wlin = jv ? W_lin[j] : 0.f;
    float zw[4], zb[4];                                  // scaled W_ih, bias
    #pragma unroll
    for (int r = 0; r < 4; ++r) {
        const float s = (r == 2) ? LOG2E2 : -LOG2E;
        zw[r] = jv ? s * W_ih[r * H + j] : 0.f;
        zb[r] = jv ? s * (b_ih[r * H + j] + b_hh[r * H + j]) : 0.f;
    }

    // ---- init: zero hb; fill XT from global x (coalesced in t) ----
    for (int i = tid; i < 2 * BW * KP; i += NTHR)
        ((_Float16*)hb)[i] = (_Float16)0.f;
    for (int i = tid; i < TT * BW; i += NTHR) {
        const int bb = i >> 10, t = i & 1023;
        XT[t][bb] = x[(size_t)(b0 + bb) * TT + t];
    }
    if (tid < 2 * BW) ((float*)&XT[TT][0])[tid] = 0.f;   // pad rows for prefetch

    float c2 = 0.f;        // scaled cell state: 2*log2e*c
    float hlast = 0.f;
    __syncthreads();

    float xt_cur = XT[0][bl];          // x for step 0
    const bool lo = (L15 < 8);

    #pragma unroll 1
    for (int tbase = 0; tbase < TT; tbase += 2) {
        #pragma unroll
        for (int half = 0; half < 2; ++half) {
            const int t = tbase + half;
            const _Float16* hp = &hb[half][bl][0];        // cur buffer
            _Float16*       np = &hb[half ^ 1][bl][0];    // next buffer

            // ---- B fragments: plain reads, k 0..31 and 32..63 ----
            const f16x8 B0 = *(const f16x8*)(hp + kq * 8);
            const f16x8 B1 = *(const f16x8*)(hp + 32 + kq * 8);

            // ---- C-init: gx for this lane's unit (exact f32, off-chain) ----
            f32x4 zc;
            #pragma unroll
            for (int r = 0; r < 4; ++r)
                zc[r] = __builtin_fmaf(zw[r], xt_cur, zb[r]);

            // ---- 4 MFMAs: two independent 2-deep chains (R13 form) ----
            f32x4 a0 = __builtin_amdgcn_mfma_f32_16x16x32_f16(A[0][0], B0, zc, 0, 0, 0);
            f32x4 a1 = __builtin_amdgcn_mfma_f32_16x16x32_f16(A[1][0], B0, zc, 0, 0, 0);
            a0 = __builtin_amdgcn_mfma_f32_16x16x32_f16(A[0][1], B1, a0, 0, 0, 0);
            a1 = __builtin_amdgcn_mfma_f32_16x16x32_f16(A[1][1], B1, a1, 0, 0, 0);

            // prefetch x for next step (off the critical chain)
            const float xt_nxt = XT[t + 1][bl];

            // ---- select this lane's accumulator (tile t0 vs t0+1) ----
            const float gi = lo ? a0[0] : a1[0];
            const float gf = lo ? a0[1] : a1[1];
            const float gg = lo ? a0[2] : a1[2];
            const float go = lo ? a0[3] : a1[3];

            // ---- fused epilogue (exp2-only), scaled-c2 form ----
            const float Ei = __builtin_amdgcn_exp2f(gi);
            const float Ef = __builtin_amdgcn_exp2f(gf);
            const float Eg = __builtin_amdgcn_exp2f(gg);
            const float Eo = __builtin_amdgcn_exp2f(go);
            const float P  = (1.0f + Ei) * (1.0f + Eg);
            const float Q2 = __builtin_fmaf(LOG2E2, Ef, LOG2E2);    // 2λ(1+Ef)
            const float num = __builtin_fmaf(c2, P, (Eg - 1.0f) * Q2);
            const float PQ  = P * (1.0f + Ef);
            c2 = num * __builtin_amdgcn_rcpf(PQ);
            const float ca = fminf(c2, 80.0f);
            const float Ec = __builtin_amdgcn_exp2f(ca);
            const float h  = (Ec - 1.0f) *
                __builtin_amdgcn_rcpf((1.0f + Eo) * (1.0f + Ec));
            hlast = h;

            np[j] = (_Float16)h;   // unguarded: pad j -> zero-A slots 50-55
            __syncthreads();
            xt_cur = xt_nxt;
        }
    }

    // ---- head: out[b] = b_lin + sum_j W_lin[j] * h[j][b] ----
    if (jv) redH[j][bl] = wlin * hlast;
    __syncthreads();
    if (tid < BW) {
        float s = b_lin[0];
        #pragma unroll 10
        for (int jj = 0; jj < H; ++jj) s += redH[jj][tid];
        out[b0 + tid] = s;
    }
}

extern "C" void kernel_launch(void* const* d_in, const int* in_sizes, int n_in,
                              void* d_out, int out_size, void* d_ws, size_t ws_size,
                              hipStream_t stream) {
    const float* x     = (const float*)d_in[0];
    const float* W_ih  = (const float*)d_in[1];
    const float* W_hh  = (const float*)d_in[2];
    const float* b_ih  = (const float*)d_in[3];
    const float* b_hh  = (const float*)d_in[4];
    const float* W_lin = (const float*)d_in[5];
    const float* b_lin = (const float*)d_in[6];
    float* out = (float*)d_out;

    dim3 grid(BATCH / BW);    // 256 blocks, 1 per CU
    dim3 block(NTHR);         // 7 waves
    lstm_kernel<<<grid, block, 0, stream>>>(x, W_ih, W_hh, b_ih, b_hh,
                                            W_lin, b_lin, out);
}